// Round 2
// baseline (410.059 us; speedup 1.0000x reference)
//
#include <hip/hip_runtime.h>
#include <hip/hip_bf16.h>
#include <math.h>

#define B_ 64
#define T_ 512
#define D_ 1024
#define M_ (B_*T_)   // 32768 rows of x flattened [B*T, D]

typedef unsigned short u16;
typedef __attribute__((ext_vector_type(8))) _Float16 f16x8;  // 8 fp16 in 4 VGPRs
typedef __attribute__((ext_vector_type(4))) float f32x4;

// fp32 -> fp16 round-to-nearest-even, return bit pattern
__device__ __forceinline__ u16 f2h(float f) {
  union { _Float16 h; u16 u; } v;
  v.h = (_Float16)f;
  return v.u;
}

// async global->LDS, 16B per lane; LDS dest = wave-uniform base + lane*16
__device__ __forceinline__ void gll16(const void* g, void* l) {
  __builtin_amdgcn_global_load_lds(
      (const __attribute__((address_space(1))) unsigned int*)g,
      (__attribute__((address_space(3))) unsigned int*)l, 16, 0, 0);
}

// ---------------- K0a: convert x fp32 -> fp16 ----------------
__global__ __launch_bounds__(256) void cvt_x_kernel(const float4* __restrict__ x,
                                                    ushort4* __restrict__ xh, int n4) {
  int i = blockIdx.x * 256 + threadIdx.x;
  if (i < n4) {
    float4 v = x[i];
    ushort4 o;
    o.x = f2h(v.x); o.y = f2h(v.y); o.z = f2h(v.z); o.w = f2h(v.w);
    xh[i] = o;
  }
}

// ---------------- K0b: W [k,n] -> Wt [n,k] fp16 (LDS-tiled transpose) ----------------
__global__ __launch_bounds__(1024) void cvt_wt_kernel(const float* __restrict__ W,
                                                      u16* __restrict__ Wt) {
  __shared__ float tile[32][33];
  int tx = threadIdx.x & 31, ty = threadIdx.x >> 5;
  int n0 = blockIdx.x * 32, k0 = blockIdx.y * 32;
  tile[ty][tx] = W[(k0 + ty) * D_ + n0 + tx];   // coalesced read along n
  __syncthreads();
  Wt[(n0 + ty) * D_ + k0 + tx] = f2h(tile[tx][ty]); // coalesced write along k
}

// ---------------- shared GEMM-BT core (m97 structure, fp16) ----------------
// C[m,n] = sum_k A[m,k] * Bt[n,k]; 128x128 tile, 256 thr (4 waves 2x2 of 64x64), BK=32
__device__ __forceinline__ void gemm_core(const u16* __restrict__ Abase,
                                          const u16* __restrict__ Bbase, int K,
                                          u16* As, u16* Bs, int tid, f32x4 acc[4][4]) {
  const int wave = tid >> 6, lane = tid & 63;
  const int q = wave * 2;                 // this wave stages LDS chunks q,q+1 of A and B
  const int row = q * 16 + (lane >> 2);   // global row for staging
  const int kc = (lane & 3) * 8;          // k-offset (elements) within BK
  const u16* gA0 = Abase + (long)row * K + kc;
  const u16* gA1 = Abase + (long)(row + 16) * K + kc;
  const u16* gB0 = Bbase + (long)row * K + kc;
  const u16* gB1 = Bbase + (long)(row + 16) * K + kc;
  u16* lA0 = As + q * 512; u16* lA1 = As + q * 512 + 512; // wave-uniform LDS bases
  u16* lB0 = Bs + q * 512; u16* lB1 = Bs + q * 512 + 512;

  const int wrow = (wave >> 1) * 64, wcol = (wave & 1) * 64;
  const int lm = lane & 15, qd = lane >> 4;
  const u16* ra = As + (wrow + lm) * 32 + qd * 8;  // A frag: A[m=lane&15][k=quad*8+j]
  const u16* rb = Bs + (wcol + lm) * 32 + qd * 8;  // B frag mirrors (Bt rows)

  for (int kt = 0; kt < K; kt += 32) {
    gll16(gA0, lA0); gll16(gA1, lA1);
    gll16(gB0, lB0); gll16(gB1, lB1);
    gA0 += 32; gA1 += 32; gB0 += 32; gB1 += 32;
    __syncthreads();                      // drains vmcnt before use (m97 pattern)
    f16x8 af[4], bfr[4];
#pragma unroll
    for (int i = 0; i < 4; i++) {
      af[i]  = *(const f16x8*)(ra + i * 16 * 32);
      bfr[i] = *(const f16x8*)(rb + i * 16 * 32);
    }
#pragma unroll
    for (int mi = 0; mi < 4; mi++)
#pragma unroll
      for (int ni = 0; ni < 4; ni++)
        acc[mi][ni] = __builtin_amdgcn_mfma_f32_16x16x32_f16(af[mi], bfr[ni], acc[mi][ni], 0, 0, 0);
    __syncthreads();                      // protect LDS before next stage
  }
}

// ---------------- K1: xw = x @ W  (M=32768, N=1024, K=1024), out fp16 ----------------
__global__ __launch_bounds__(256, 2) void gemm1_kernel(const u16* __restrict__ xh,
                                                       const u16* __restrict__ wt,
                                                       u16* __restrict__ xw) {
  __shared__ u16 As[128 * 32], Bs[128 * 32];
  f32x4 acc[4][4] = {};
  const int tid = threadIdx.x;
  const long m0 = (long)blockIdx.y * 128;
  const long n0 = (long)blockIdx.x * 128;
  gemm_core(xh + m0 * D_, wt + n0 * D_, D_, As, Bs, tid, acc);

  const int wave = tid >> 6, lane = tid & 63;
  const int wrow = (wave >> 1) * 64, wcol = (wave & 1) * 64;
  const int lm = lane & 15, qd = lane >> 4;
#pragma unroll
  for (int mi = 0; mi < 4; mi++)
#pragma unroll
    for (int ni = 0; ni < 4; ni++) {
      long m = m0 + wrow + mi * 16 + qd * 4;   // C/D: row=(lane>>4)*4+reg
      long n = n0 + wcol + ni * 16 + lm;       //      col=lane&15
      u16* p = xw + m * D_ + n;
#pragma unroll
      for (int r = 0; r < 4; r++) p[(long)r * D_] = f2h(acc[mi][ni][r]);
    }
}

// ---------------- K2: batched eij tile + fused tanh*cv reduction -> scores ----------------
__global__ __launch_bounds__(256, 2) void gemm2_kernel(const u16* __restrict__ xw,
                                                       const u16* __restrict__ xh,
                                                       const float* __restrict__ bias,
                                                       const float* __restrict__ cv,
                                                       float* __restrict__ scores) {
  __shared__ u16 As[128 * 32], Bs[128 * 32];
  f32x4 acc[4][4] = {};
  const int bx = blockIdx.x;                 // 64 batches * 4 t-tiles * 4 s-tiles
  const int bb = bx >> 4, tt = (bx >> 2) & 3, st = bx & 3;
  const int tid = threadIdx.x;
  const long arow = (long)bb * T_ + tt * 128;
  const long brow = (long)bb * T_ + st * 128;
  gemm_core(xw + arow * D_, xh + brow * D_, D_, As, Bs, tid, acc);

  const int wave = tid >> 6, lane = tid & 63;
  const int wrow = (wave >> 1) * 64, wcol = (wave & 1) * 64;
  const int lm = lane & 15, qd = lane >> 4;
  float cvv[4], bv[4];
#pragma unroll
  for (int ni = 0; ni < 4; ni++) {
    int s = st * 128 + wcol + ni * 16 + lm;
    cvv[ni] = cv[s];
    bv[ni] = bias[s];
  }
#pragma unroll
  for (int mi = 0; mi < 4; mi++) {
#pragma unroll
    for (int r = 0; r < 4; r++) {
      float p = 0.f;
#pragma unroll
      for (int ni = 0; ni < 4; ni++) p += tanhf(acc[mi][ni][r] + bv[ni]) * cvv[ni];
      // sum across the 16 cols held by this quad's lanes
      p += __shfl_xor(p, 1); p += __shfl_xor(p, 2);
      p += __shfl_xor(p, 4); p += __shfl_xor(p, 8);
      if (lm == 0)
        atomicAdd(&scores[bb * T_ + tt * 128 + wrow + mi * 16 + qd * 4 + r], p);
    }
  }
}

// ---------------- K3: masked softmax over T per batch (with mask-dtype detection) -------
__global__ __launch_bounds__(512) void softmax_kernel(const float* __restrict__ scores,
                                                      const unsigned char* __restrict__ m8,
                                                      float* __restrict__ a_out) {
  const int b = blockIdx.x, t = threadIdx.x;   // 512 threads = 8 waves
  __shared__ int nonz;
  __shared__ float redm[8], reds[8];
  if (t == 0) nonz = 0;
  __syncthreads();
  // detect int32-vs-uint8 bool storage: int32 => upper 3 bytes of each word are 0
  unsigned char c = m8[t * 4 + 1] | m8[t * 4 + 2] | m8[t * 4 + 3];
  if (c) atomicOr(&nonz, 1);
  __syncthreads();
  const bool is_i32 = (nonz == 0);
  const int idx = b * T_ + t;
  const bool valid = is_i32 ? (m8[(long)idx * 4] != 0) : (m8[idx] != 0);

  float val = valid ? scores[idx] : -INFINITY;
  float m = val;
#pragma unroll
  for (int o = 32; o > 0; o >>= 1) m = fmaxf(m, __shfl_xor(m, o));
  const int wv = t >> 6, ln = t & 63;
  if (ln == 0) redm[wv] = m;
  __syncthreads();
  float rowmax = redm[0];
#pragma unroll
  for (int i = 1; i < 8; i++) rowmax = fmaxf(rowmax, redm[i]);

  float e = valid ? expf(val - rowmax) : 0.f;
  float ssum = e;
#pragma unroll
  for (int o = 32; o > 0; o >>= 1) ssum += __shfl_xor(ssum, o);
  if (ln == 0) reds[wv] = ssum;
  __syncthreads();
  float tot = 0.f;
#pragma unroll
  for (int i = 0; i < 8; i++) tot += reds[i];
  a_out[idx] = e / tot;
}

// ---------------- K4: out[b,d] = sum_t a[b,t] * x[b,t,d] ----------------
__global__ __launch_bounds__(256) void wsum_kernel(const float* __restrict__ x,
                                                   const float* __restrict__ a,
                                                   float* __restrict__ out) {
  const int b = blockIdx.x, sl = blockIdx.y, tid = threadIdx.x; // grid (64, 8)
  const float4* xp = (const float4*)(x + (long)b * T_ * D_);
  float4 acc = make_float4(0.f, 0.f, 0.f, 0.f);
  for (int t = sl * 64; t < sl * 64 + 64; t++) {
    float av = a[b * T_ + t];
    float4 xv = xp[t * (D_ / 4) + tid];
    acc.x += av * xv.x; acc.y += av * xv.y; acc.z += av * xv.z; acc.w += av * xv.w;
  }
  float* op = out + (long)b * D_ + tid * 4;
  atomicAdd(op + 0, acc.x); atomicAdd(op + 1, acc.y);
  atomicAdd(op + 2, acc.z); atomicAdd(op + 3, acc.w);
}

extern "C" void kernel_launch(void* const* d_in, const int* in_sizes, int n_in,
                              void* d_out, int out_size, void* d_ws, size_t ws_size,
                              hipStream_t stream) {
  const float* x = (const float*)d_in[0];
  const unsigned char* mask = (const unsigned char*)d_in[1];
  const float* W = (const float*)d_in[2];
  const float* cv = (const float*)d_in[3];     // context_vector [T,1] -> flat [T]
  const float* bias = (const float*)d_in[4];   // b [T] (zeros, but honored)

  float* out = (float*)d_out;                  // [B,D] = 65536 floats
  float* a_out = out + (size_t)B_ * D_;        // [B,T] = 32768 floats

  // workspace layout (130.2 MiB total)
  char* ws = (char*)d_ws;
  u16* xh = (u16*)(ws);                         // fp16 x       [M_, D_]  64 MiB
  u16* wt = (u16*)(ws + 67108864);              // fp16 W^T     [D_, D_]   2 MiB
  u16* xw = (u16*)(ws + 69206016);              // fp16 x@W     [M_, D_]  64 MiB
  float* scores = (float*)(ws + 136314880);     // fp32 scores  [B_, T_] 128 KiB

  hipMemsetAsync(scores, 0, (size_t)M_ * sizeof(float), stream);
  hipMemsetAsync(out, 0, (size_t)B_ * D_ * sizeof(float), stream);

  cvt_x_kernel<<<(M_ * D_ / 4 + 255) / 256, 256, 0, stream>>>((const float4*)x,
                                                              (ushort4*)xh, M_ * D_ / 4);
  cvt_wt_kernel<<<dim3(32, 32), 1024, 0, stream>>>(W, wt);
  gemm1_kernel<<<dim3(D_ / 128, M_ / 128), 256, 0, stream>>>(xh, wt, xw);
  gemm2_kernel<<<B_ * 16, 256, 0, stream>>>(xw, xh, bias, cv, scores);
  softmax_kernel<<<B_, 512, 0, stream>>>(scores, mask, a_out);
  wsum_kernel<<<dim3(B_, 8), 256, 0, stream>>>(x, a_out, out);
}